// Round 5
// baseline (220.944 us; speedup 1.0000x reference)
//
#include <hip/hip_runtime.h>
#include <hip/hip_bf16.h>
#include <math.h>

// out[r][c] = tanh( sum_k 0.25*tanh(kw[k]) * exp(-0.5*((c/L - mean_k)/0.1)^2 - log(0.1*sqrt(2pi))) )
// independent of r and of `values` content. R5: single fused kernel — each
// thread computes its <=NV pattern f32x4 vectors in-register (fast exp/tanh,
// abs err ~1e-6 << 9.96e-3 threshold), then streams cached 16B stores.
// Removes the row-kernel launch + serialization and the d_ws round-trip.
// -log(0.1*sqrt(2*pi)) = 1.3836465597...
#define LOG_NORM_NEG 1.3836465597f
#define NV 4  // pattern vectors per thread: ceil(nvec/256); nvec=1023 -> 4

typedef float f32x4 __attribute__((ext_vector_type(4)));

__device__ __forceinline__ float fast_tanh(float x) {
    // tanh(x) = 1 - 2/(exp(2x)+1); __expf -> v_exp_f32. |x|<=50 here, no overflow.
    float e = __expf(2.0f * x);
    return 1.0f - 2.0f / (e + 1.0f);
}

__device__ __forceinline__ float col_value(int c, int L, const float* w) {
    const float means[6] = {0.0f, 0.2f, 0.4f, 0.6f, 0.8f, 1.0f};
    float pos = (float)c / (float)L;
    float s = 0.0f;
#pragma unroll
    for (int k = 0; k < 6; ++k) {
        float z = (pos - means[k]) * 10.0f;              // / std (0.1)
        float pdf = __expf(fmaf(-0.5f * z, z, LOG_NORM_NEG));
        s = fmaf(w[k], pdf, s);
    }
    return fast_tanh(s);
}

__global__ __launch_bounds__(256) void locate_fused2(
    const float* __restrict__ kw, f32x4* __restrict__ out4,
    int L, int pairs, int ppb) {
    const int nvec = (2 * L) / 4;          // 1023 for L=2046
    const int tid  = threadIdx.x;

    float w[6];
#pragma unroll
    for (int k = 0; k < 6; ++k) w[k] = 0.25f * fast_tanh(kw[k]);

    f32x4 v[NV];
#pragma unroll
    for (int i = 0; i < NV; ++i) {
        int j = tid + i * 256;
        if (j < nvec) {
            int c = (4 * j) % L;           // one modulo per pattern vector
            f32x4 t;
            t.x = col_value(c, L, w); ++c; if (c == L) c = 0;
            t.y = col_value(c, L, w); ++c; if (c == L) c = 0;
            t.z = col_value(c, L, w); ++c; if (c == L) c = 0;
            t.w = col_value(c, L, w);
            v[i] = t;
        }
    }

    const int p0 = blockIdx.x * ppb;
    for (int k = 0; k < ppb; ++k) {
        int p = p0 + k;
        if (p >= pairs) return;
        f32x4* dst = out4 + (size_t)p * (size_t)nvec;
#pragma unroll
        for (int i = 0; i < NV; ++i) {
            int j = tid + i * 256;
            if (j < nvec) dst[j] = v[i];
        }
    }
}

// Generic fallback (shapes where NV*256 < nvec or bs odd): per-element compute.
__global__ void locate_fused_scalar(const float* __restrict__ kw,
                                    float* __restrict__ out,
                                    unsigned int L, unsigned int total) {
    unsigned int i = blockIdx.x * blockDim.x + threadIdx.x;
    if (i >= total) return;
    float w[6];
#pragma unroll
    for (int k = 0; k < 6; ++k) w[k] = 0.25f * fast_tanh(kw[k]);
    out[i] = col_value((int)(i % L), (int)L, w);
}

extern "C" void kernel_launch(void* const* d_in, const int* in_sizes, int n_in,
                              void* d_out, int out_size, void* d_ws, size_t ws_size,
                              hipStream_t stream) {
    const float* kw = (const float*)d_in[1];   // kernel_weights, 6 floats
    float* out = (float*)d_out;

    // bs*L_in = in_sizes[0], bs*(L_in-2) = out_size => bs = (n_values - out)/2
    long long n_values = in_sizes[0];
    long long bs = (n_values - (long long)out_size) / 2;
    int L = (int)((long long)out_size / bs);   // 2046

    bool pair_ok = (bs % 2 == 0) && ((2 * L) % 4 == 0) && ((2 * L) / 4 <= NV * 256);
    if (pair_ok) {
        int pairs = (int)(bs / 2);                       // 8192
        int ppb = 2;                                     // -> 4096 blocks
        int blocks = (pairs + ppb - 1) / ppb;
        locate_fused2<<<blocks, 256, 0, stream>>>(
            kw, (f32x4*)out, L, pairs, ppb);
    } else {
        unsigned int total = (unsigned int)out_size;
        int threads = 256;
        int blocks = (int)((total + threads - 1) / threads);
        locate_fused_scalar<<<blocks, threads, 0, stream>>>(
            kw, out, (unsigned int)L, total);
    }
}

// Round 6
// 203.077 us; speedup vs baseline: 1.0880x; 1.0880x over previous
//
#include <hip/hip_runtime.h>
#include <hip/hip_bf16.h>
#include <math.h>

// out[r][c] = tanh( sum_k 0.25*tanh(kw[k]) * exp(-0.5*((c/L - mean_k)/0.1)^2 - log(0.1*sqrt(2pi))) )
// independent of r and of `values` content -> compute row once (tiny kernel),
// broadcast with cached 16B streaming stores.
// R6 = revert to R4 (best: 204.2 us). R5's single-kernel fusion regressed
// (+17 us): per-thread recompute of the row multiplied transcendental work
// ~8000x to save one ~3 us launch. Keep the two-kernel split.
// -log(0.1*sqrt(2*pi)) = 1.3836465597...
#define LOG_NORM_NEG 1.3836465597f

typedef float f32x4 __attribute__((ext_vector_type(4)));

__global__ void locate_row_kernel(const float* __restrict__ kw,
                                  float* __restrict__ row, int L) {
    int c = blockIdx.x * blockDim.x + threadIdx.x;
    if (c >= L) return;
    const float means[6] = {0.0f, 0.2f, 0.4f, 0.6f, 0.8f, 1.0f};
    float pos = (float)c / (float)L;
    float s = 0.0f;
#pragma unroll
    for (int k = 0; k < 6; ++k) {
        float w = 0.25f * tanhf(kw[k]);
        float z = (pos - means[k]) * 10.0f;          // / std (0.1)
        float pdf = expf(fmaf(-0.5f * z, z, LOG_NORM_NEG));
        s = fmaf(w, pdf, s);
    }
    row[c] = tanhf(s);
}

// Broadcast: two consecutive rows = 2L floats = nvec f32x4 (16B-aligned since
// 2L % 4 == 0 and pair stride 2L*4 bytes is a multiple of 16).
// Each thread materializes its <=NV pattern vectors ONCE in registers (L2-hit
// gathers), then the hot loop is pure cached 16B stores. Cached (not nt):
// the 128 MiB output flows through L2/Infinity Cache like the 6.7 TB/s
// harness fill kernels; nt (R3) was ~6 us slower.
#define NV 4  // pattern vectors per thread: ceil(nvec/256); nvec=1023 -> 4

__global__ __launch_bounds__(256) void locate_broadcast2(
    const float* __restrict__ row, f32x4* __restrict__ out4,
    int L, int pairs, int ppb) {
    const int nvec = (2 * L) / 4;          // 1023 for L=2046
    const int tid  = threadIdx.x;

    f32x4 v[NV];
#pragma unroll
    for (int i = 0; i < NV; ++i) {
        int j = tid + i * 256;
        if (j < nvec) {
            int c = (4 * j) % L;           // one modulo per pattern vector only
            f32x4 t;
            t.x = row[c]; ++c; if (c == L) c = 0;
            t.y = row[c]; ++c; if (c == L) c = 0;
            t.z = row[c]; ++c; if (c == L) c = 0;
            t.w = row[c];
            v[i] = t;
        }
    }

    const int p0 = blockIdx.x * ppb;
    for (int k = 0; k < ppb; ++k) {
        int p = p0 + k;
        if (p >= pairs) return;
        f32x4* dst = out4 + (size_t)p * (size_t)nvec;
#pragma unroll
        for (int i = 0; i < NV; ++i) {
            int j = tid + i * 256;
            if (j < nvec) dst[j] = v[i];
        }
    }
}

// Generic fallback (shapes where NV*256 < nvec or bs odd): per-element gather.
__global__ void locate_fused_kernel(const float* __restrict__ row,
                                    float* __restrict__ out,
                                    unsigned int L, unsigned int total) {
    unsigned int i = blockIdx.x * blockDim.x + threadIdx.x;
    if (i >= total) return;
    out[i] = row[i % L];
}

extern "C" void kernel_launch(void* const* d_in, const int* in_sizes, int n_in,
                              void* d_out, int out_size, void* d_ws, size_t ws_size,
                              hipStream_t stream) {
    const float* kw = (const float*)d_in[1];   // kernel_weights, 6 floats
    float* out = (float*)d_out;

    // bs*L_in = in_sizes[0], bs*(L_in-2) = out_size => bs = (n_values - out)/2
    long long n_values = in_sizes[0];
    long long bs = (n_values - (long long)out_size) / 2;
    int L = (int)((long long)out_size / bs);   // 2046

    float* row = (float*)d_ws;                 // L floats, ws is plenty
    {
        int threads = 256;
        int blocks = (L + threads - 1) / threads;
        locate_row_kernel<<<blocks, threads, 0, stream>>>(kw, row, L);
    }

    bool pair_ok = (bs % 2 == 0) && ((2 * L) % 4 == 0) && ((2 * L) / 4 <= NV * 256);
    if (pair_ok) {
        int pairs = (int)(bs / 2);                       // 8192
        int ppb = 2;                                     // -> 4096 blocks
        int blocks = (pairs + ppb - 1) / ppb;
        locate_broadcast2<<<blocks, 256, 0, stream>>>(
            row, (f32x4*)out, L, pairs, ppb);
    } else {
        unsigned int total = (unsigned int)out_size;
        int threads = 256;
        int blocks = (int)((total + threads - 1) / threads);
        locate_fused_kernel<<<blocks, threads, 0, stream>>>(
            row, out, (unsigned int)L, total);
    }
}